// Round 1
// baseline (771.626 us; speedup 1.0000x reference)
//
#include <hip/hip_runtime.h>

// Problem constants
#define TT 16
#define NN 50000
#define FF 64
#define EE 131072
#define NR (TT*NN)            // 800000 (j,row) pairs
#define NEDGE (TT*EE)         // 2097152 edges total
#define SCAN_NBLK ((NR + 1023) / 1024)   // 782

typedef __attribute__((ext_vector_type(8))) short bf16x8;
typedef __attribute__((ext_vector_type(4))) float f32x4;

__device__ __forceinline__ unsigned short f2bf(float f) {
    union { float f; unsigned u; } v; v.f = f;
    return (unsigned short)((v.u + 0x7FFFu + ((v.u >> 16) & 1u)) >> 16);  // RNE
}

// ---------------------------------------------------------------------------
// K1: Yt[k][node][fo] = sum_s M[k,s] * sum_fi x[s][node][fi] * W[fi][fo]
// One wave per node. Proj by W via bf16 MFMA, time-mix in f32, store bf16.
// ---------------------------------------------------------------------------
__global__ __launch_bounds__(256) void k1_proj_mix(
    const float* __restrict__ x, const float* __restrict__ M,
    const float* __restrict__ W, unsigned short* __restrict__ Yt)
{
    __shared__ short xt_lds[4][16*72];   // per-wave bf16 x-tile [s][fi], rowstride 144B (16B-aligned rows)
    __shared__ float p_lds[4][16*68];    // per-wave f32 P-tile [s][fo], rowstride 68 floats

    const int tid  = threadIdx.x;
    const int wid  = tid >> 6;
    const int lane = tid & 63;
    const int col  = lane & 15;   // MFMA m/n index
    const int grp  = lane >> 4;   // MFMA k-group

    // Preload W as MFMA B-fragments: B[kdim=fi][n=fo]; lane l elem j -> fi=(q*32+grp*8+j), fo=t*16+col
    bf16x8 bw[2][4];
#pragma unroll
    for (int q = 0; q < 2; ++q)
#pragma unroll
        for (int t = 0; t < 4; ++t)
#pragma unroll
            for (int j = 0; j < 8; ++j)
                bw[q][t][j] = (short)f2bf(W[(q*32 + grp*8 + j)*FF + t*16 + col]);

    short* myxt = xt_lds[wid];
    float* myp  = p_lds[wid];
    const int nwaves = gridDim.x * 4;

    for (int node = blockIdx.x*4 + wid; node < NN; node += nwaves) {
        // ---- stage x rows to LDS as bf16, layout [s][fi] (coalesced 256B global loads) ----
#pragma unroll
        for (int s = 0; s < 16; ++s) {
            float v = x[((size_t)s*NN + node)*FF + lane];
            myxt[s*72 + lane] = (short)f2bf(v);
        }
        __builtin_amdgcn_sched_barrier(0);   // LDS writes before A-frag reads (same wave, block reorder)

        // ---- P[s][fo] = x[s][:] @ W : A-frag lane l = row (col), fi=(q*32+grp*8+j) ----
        f32x4 acc[4];
#pragma unroll
        for (int t = 0; t < 4; ++t) acc[t] = (f32x4){0.f, 0.f, 0.f, 0.f};
#pragma unroll
        for (int q = 0; q < 2; ++q) {
            bf16x8 af = *reinterpret_cast<const bf16x8*>(
                reinterpret_cast<const char*>(myxt) + (col*144 + q*64 + grp*16));
#pragma unroll
            for (int t = 0; t < 4; ++t)
                acc[t] = __builtin_amdgcn_mfma_f32_16x16x32_bf16(af, bw[q][t], acc[t], 0, 0, 0);
        }
        __builtin_amdgcn_sched_barrier(0);

        // ---- transpose P via LDS (f32, no quantization): D lane holds row s=grp*4+rr, col fo=t*16+col ----
#pragma unroll
        for (int t = 0; t < 4; ++t)
#pragma unroll
            for (int rr = 0; rr < 4; ++rr)
                myp[(grp*4 + rr)*68 + t*16 + col] = acc[t][rr];
        __builtin_amdgcn_sched_barrier(0);   // LDS writes before reads

        float p[16];
#pragma unroll
        for (int s = 0; s < 16; ++s) p[s] = myp[s*68 + lane];

        // ---- time mix in f32 (M via scalar loads), store Yt bf16 (128B coalesced) ----
#pragma unroll
        for (int k = 0; k < 16; ++k) {
            float a = 0.f;
#pragma unroll
            for (int s = 0; s < 16; ++s) a = fmaf(M[k*16 + s], p[s], a);
            Yt[((size_t)k*NN + node)*FF + lane] = f2bf(a);
        }
    }
}

// ---------------------------------------------------------------------------
// CSR build: count -> scan (3 phase) -> fill
// ---------------------------------------------------------------------------
__global__ __launch_bounds__(256) void count_kernel(const int* __restrict__ rows,
                                                    int* __restrict__ cnt)
{
    int i = blockIdx.x*256 + threadIdx.x;
    const int stride = gridDim.x*256;
    for (; i < NEDGE; i += stride) {
        const int j = i >> 17;            // EE = 2^17
        atomicAdd(&cnt[j*NN + rows[i]], 1);
    }
}

__global__ __launch_bounds__(256) void scan1(const int* __restrict__ cnt, int* __restrict__ part)
{
    __shared__ int sd[256];
    const int t = threadIdx.x;
    const int base = blockIdx.x*1024 + t*4;
    int s = 0;
    if (base + 3 < NR) {
        int4 v = *reinterpret_cast<const int4*>(cnt + base);
        s = v.x + v.y + v.z + v.w;
    } else if (base < NR) {
        for (int u = 0; u < 4; ++u) if (base + u < NR) s += cnt[base + u];
    }
    sd[t] = s; __syncthreads();
#pragma unroll
    for (int o = 128; o > 0; o >>= 1) {
        if (t < o) sd[t] += sd[t + o];
        __syncthreads();
    }
    if (t == 0) part[blockIdx.x] = sd[0];
}

__global__ __launch_bounds__(1024) void scan2(int* __restrict__ part)
{
    __shared__ int sd[1024];
    const int t = threadIdx.x;
    sd[t] = (t < SCAN_NBLK) ? part[t] : 0;
    __syncthreads();
#pragma unroll
    for (int o = 1; o < 1024; o <<= 1) {
        int v = (t >= o) ? sd[t - o] : 0;
        __syncthreads();
        sd[t] += v;
        __syncthreads();
    }
    part[t] = (t == 0) ? 0 : sd[t - 1];   // exclusive block prefix
}

__global__ __launch_bounds__(256) void scan3(const int* __restrict__ cnt, const int* __restrict__ part,
                                             int* __restrict__ offs, int* __restrict__ cur)
{
    __shared__ int sd[256];
    const int t = threadIdx.x;
    const int base = blockIdx.x*1024 + t*4;
    int v0 = 0, v1 = 0, v2 = 0, v3 = 0;
    if (base + 3 < NR) {
        int4 v = *reinterpret_cast<const int4*>(cnt + base);
        v0 = v.x; v1 = v.y; v2 = v.z; v3 = v.w;
    } else if (base < NR) {
        v0 = cnt[base];
        if (base + 1 < NR) v1 = cnt[base + 1];
        if (base + 2 < NR) v2 = cnt[base + 2];
    }
    sd[t] = v0 + v1 + v2 + v3;
    __syncthreads();
#pragma unroll
    for (int o = 1; o < 256; o <<= 1) {
        int vv = (t >= o) ? sd[t - o] : 0;
        __syncthreads();
        sd[t] += vv;
        __syncthreads();
    }
    const int excl = (t == 0) ? 0 : sd[t - 1];
    const int off = part[blockIdx.x] + excl;
    const int o0 = off, o1 = off + v0, o2 = off + v0 + v1, o3 = off + v0 + v1 + v2;
    if (base + 3 < NR) {
        int4 ov; ov.x = o0; ov.y = o1; ov.z = o2; ov.w = o3;
        *reinterpret_cast<int4*>(offs + base) = ov;
        *reinterpret_cast<int4*>(cur + base) = ov;
    } else if (base < NR) {
        offs[base] = o0; cur[base] = o0;
        if (base + 1 < NR) { offs[base+1] = o1; cur[base+1] = o1; }
        if (base + 2 < NR) { offs[base+2] = o2; cur[base+2] = o2; }
    }
}

__global__ __launch_bounds__(256) void fill_kernel(const int* __restrict__ rows,
                                                   const int* __restrict__ cols,
                                                   const float* __restrict__ vals,
                                                   int* __restrict__ cur,
                                                   int2* __restrict__ csr)
{
    int i = blockIdx.x*256 + threadIdx.x;
    const int stride = gridDim.x*256;
    for (; i < NEDGE; i += stride) {
        const int j = i >> 17;
        const int pos = atomicAdd(&cur[j*NN + rows[i]], 1);
        int2 ent; ent.x = cols[i]; ent.y = __float_as_int(vals[i]);
        csr[pos] = ent;
    }
}

// ---------------------------------------------------------------------------
// K2: out[k][r][:] = sum_{d=0..2, j=k-d>=0} M[k,j] * sum_{e in CSR_j(r)} v_e * Yt[k][c_e][:]
// One wave handles 4 rows (16 lanes x ushort4 each). Pure gather, no atomics.
// ---------------------------------------------------------------------------
__global__ __launch_bounds__(256) void k2_spmm(
    const unsigned short* __restrict__ Yt, const float* __restrict__ M,
    const int* __restrict__ offs, const int* __restrict__ cnt,
    const int2* __restrict__ csr, float* __restrict__ out)
{
    const int wid  = threadIdx.x >> 6;
    const int lane = threadIdx.x & 63;
    const int grp  = lane >> 4;   // row within wave
    const int fq   = lane & 15;   // feature quad: f = fq*4 .. fq*4+3
    const int k = blockIdx.y;
    const int r = blockIdx.x*16 + wid*4 + grp;    // 3125*16 = 50000 exact
    const unsigned short* Yb = Yt + (size_t)k*NN*FF;

    int bases[3], ns[3]; float wgt[3];
#pragma unroll
    for (int d = 0; d < 3; ++d) {
        const int j = k - d;
        const bool ok = (j >= 0);
        const int jc = ok ? j : 0;
        bases[d] = offs[jc*NN + r];
        ns[d]    = ok ? cnt[jc*NN + r] : 0;
        wgt[d]   = ok ? M[k*16 + jc] : 0.f;
    }

    float a0 = 0.f, a1 = 0.f, a2 = 0.f, a3 = 0.f;
#pragma unroll
    for (int d = 0; d < 3; ++d) {
        const int n = ns[d];
        const int base = bases[d];
        const float w = wgt[d];
        int2 ent;
        if (n > 0) ent = csr[base];
        for (int e = 0; e < n; ++e) {
            int2 nxt = ent;
            if (e + 1 < n) nxt = csr[base + e + 1];   // 1-ahead prefetch of next edge
            const float wv = w * __int_as_float(ent.y);
            const uint2 uv = *reinterpret_cast<const uint2*>(Yb + (size_t)ent.x*FF + fq*4);
            a0 = fmaf(wv, __uint_as_float((uv.x & 0xFFFFu) << 16), a0);
            a1 = fmaf(wv, __uint_as_float(uv.x & 0xFFFF0000u), a1);
            a2 = fmaf(wv, __uint_as_float((uv.y & 0xFFFFu) << 16), a2);
            a3 = fmaf(wv, __uint_as_float(uv.y & 0xFFFF0000u), a3);
            ent = nxt;
        }
    }
    float4 res; res.x = a0; res.y = a1; res.z = a2; res.w = a3;
    *reinterpret_cast<float4*>(out + ((size_t)k*NN + r)*FF + fq*4) = res;
}

// ---------------------------------------------------------------------------
extern "C" void kernel_launch(void* const* d_in, const int* in_sizes, int n_in,
                              void* d_out, int out_size, void* d_ws, size_t ws_size,
                              hipStream_t stream) {
    (void)in_sizes; (void)n_in; (void)out_size; (void)ws_size;
    const float* x     = (const float*)d_in[0];
    const float* M     = (const float*)d_in[1];
    const float* avals = (const float*)d_in[2];
    const float* W     = (const float*)d_in[3];
    const int*   arows = (const int*)d_in[4];
    const int*   acols = (const int*)d_in[5];
    float* out = (float*)d_out;

    // workspace carve (total ~128.8 MB)
    char* ws = (char*)d_ws;
    size_t o = 0;
    unsigned short* Yt = (unsigned short*)(ws + o); o += (size_t)TT*NN*FF*2;  // 102.4 MB
    o = (o + 255) & ~(size_t)255;
    int* cnt  = (int*)(ws + o); o += (size_t)NR*4; o = (o + 255) & ~(size_t)255;
    int* offs = (int*)(ws + o); o += (size_t)NR*4; o = (o + 255) & ~(size_t)255;
    int* cur  = (int*)(ws + o); o += (size_t)NR*4; o = (o + 255) & ~(size_t)255;
    int* part = (int*)(ws + o); o += 4096;          o = (o + 255) & ~(size_t)255;
    int2* csr = (int2*)(ws + o);                    // 16.8 MB

    hipMemsetAsync(cnt, 0, (size_t)NR*4, stream);
    hipLaunchKernelGGL(k1_proj_mix, dim3(2048), dim3(256), 0, stream, x, M, W, Yt);
    hipLaunchKernelGGL(count_kernel, dim3(2048), dim3(256), 0, stream, arows, cnt);
    hipLaunchKernelGGL(scan1, dim3(SCAN_NBLK), dim3(256), 0, stream, cnt, part);
    hipLaunchKernelGGL(scan2, dim3(1), dim3(1024), 0, stream, part);
    hipLaunchKernelGGL(scan3, dim3(SCAN_NBLK), dim3(256), 0, stream, cnt, part, offs, cur);
    hipLaunchKernelGGL(fill_kernel, dim3(2048), dim3(256), 0, stream, arows, acols, avals, cur, csr);
    hipLaunchKernelGGL(k2_spmm, dim3(3125, 16), dim3(256), 0, stream, Yt, M, offs, cnt, csr, out);
}

// Round 2
// 550.106 us; speedup vs baseline: 1.4027x; 1.4027x over previous
//
#include <hip/hip_runtime.h>

// Problem constants
#define TT 16
#define NN 50000
#define FF 64
#define EE 131072
#define NR (TT*NN)            // 800000 (j,row) pairs
#define NEDGE (TT*EE)         // 2097152 edges total
#define SCAN_NBLK ((NR + 1023) / 1024)   // 782

typedef __attribute__((ext_vector_type(8))) short bf16x8;
typedef __attribute__((ext_vector_type(4))) short bf16x4;
typedef __attribute__((ext_vector_type(4))) float f32x4;

__device__ __forceinline__ unsigned short f2bf(float f) {
    union { float f; unsigned u; } v; v.f = f;
    return (unsigned short)((v.u + 0x7FFFu + ((v.u >> 16) & 1u)) >> 16);  // RNE
}

// K=16 bf16 MFMA: D[16x16] = A[16x16] * B[16x16] + C.
// A: lane holds A[m=lane&15][k=(lane>>4)*4+j]; B: B[k=(lane>>4)*4+j][n=lane&15];
// C/D: row=(lane>>4)*4+reg, col=lane&15 (shape-determined, same as 16x16x32).
__device__ __forceinline__ f32x4 mfma16x16x16bf16(bf16x4 a, bf16x4 b, f32x4 c) {
#if __has_builtin(__builtin_amdgcn_mfma_f32_16x16x16bf16_1k)
    return __builtin_amdgcn_mfma_f32_16x16x16bf16_1k(a, b, c, 0, 0, 0);
#elif __has_builtin(__builtin_amdgcn_mfma_f32_16x16x16_bf16)
    return __builtin_amdgcn_mfma_f32_16x16x16_bf16(a, b, c, 0, 0, 0);
#else
    f32x4 d;
    asm volatile("v_mfma_f32_16x16x16_bf16 %0, %1, %2, %3\n\ts_nop 7\n\ts_nop 7"
                 : "=&v"(d) : "v"(a), "v"(b), "v"(c));
    return d;
#endif
}

// ---------------------------------------------------------------------------
// K1: Yt[k][node][fo] = sum_s M[k,s] * sum_fi x[s][node][fi] * W[fi][fo]
// One wave per node, fully in-register: global->A-frag, proj MFMA (K=32 x2),
// P-acc feeds directly as B-frag of the mix MFMA (K=16), store bf16.
// ---------------------------------------------------------------------------
__global__ __launch_bounds__(256) void k1_proj_mix(
    const float* __restrict__ x, const float* __restrict__ M,
    const float* __restrict__ W, unsigned short* __restrict__ Yt)
{
    const int tid  = threadIdx.x;
    const int wid  = tid >> 6;
    const int lane = tid & 63;
    const int col  = lane & 15;   // MFMA m/n index
    const int grp  = lane >> 4;   // MFMA k-group

    // W as B-frags for 16x16x32: lane holds B[k=q*32+grp*8+j][n=t*16+col]
    bf16x8 bw[2][4];
#pragma unroll
    for (int q = 0; q < 2; ++q)
#pragma unroll
        for (int t = 0; t < 4; ++t)
#pragma unroll
            for (int j = 0; j < 8; ++j)
                bw[q][t][j] = (short)f2bf(W[(q*32 + grp*8 + j)*FF + t*16 + col]);

    // M as A-frag for 16x16x16: lane holds A[m=col][k=grp*4+j] = M[col][grp*4+j]
    bf16x4 mf;
#pragma unroll
    for (int j = 0; j < 4; ++j) mf[j] = (short)f2bf(M[col*16 + grp*4 + j]);

    const f32x4 zero = {0.f, 0.f, 0.f, 0.f};
    const int nwaves = gridDim.x * 4;

    for (int node = blockIdx.x*4 + wid; node < NN; node += nwaves) {
        // ---- load x rows direct to A-frags: lane reads row s=col, fi = q*32+grp*8+(0..7) ----
        const float* xb = x + (size_t)col*NN*FF + (size_t)node*FF + grp*8;
        float4 v0 = *reinterpret_cast<const float4*>(xb);
        float4 v1 = *reinterpret_cast<const float4*>(xb + 4);
        float4 v2 = *reinterpret_cast<const float4*>(xb + 32);
        float4 v3 = *reinterpret_cast<const float4*>(xb + 36);
        bf16x8 a0, a1;
        a0[0] = (short)f2bf(v0.x); a0[1] = (short)f2bf(v0.y);
        a0[2] = (short)f2bf(v0.z); a0[3] = (short)f2bf(v0.w);
        a0[4] = (short)f2bf(v1.x); a0[5] = (short)f2bf(v1.y);
        a0[6] = (short)f2bf(v1.z); a0[7] = (short)f2bf(v1.w);
        a1[0] = (short)f2bf(v2.x); a1[1] = (short)f2bf(v2.y);
        a1[2] = (short)f2bf(v2.z); a1[3] = (short)f2bf(v2.w);
        a1[4] = (short)f2bf(v3.x); a1[5] = (short)f2bf(v3.y);
        a1[6] = (short)f2bf(v3.z); a1[7] = (short)f2bf(v3.w);

        // ---- P[s][fo] = X @ W via 16x16x32 MFMA (K=64 in 2 steps, 4 fo-tiles) ----
        f32x4 acc[4];
#pragma unroll
        for (int t = 0; t < 4; ++t) acc[t] = zero;
#pragma unroll
        for (int t = 0; t < 4; ++t)
            acc[t] = __builtin_amdgcn_mfma_f32_16x16x32_bf16(a0, bw[0][t], acc[t], 0, 0, 0);
#pragma unroll
        for (int t = 0; t < 4; ++t)
            acc[t] = __builtin_amdgcn_mfma_f32_16x16x32_bf16(a1, bw[1][t], acc[t], 0, 0, 0);

        // ---- Y = M @ P via 16x16x16 MFMA: P C-layout IS the B-frag layout ----
#pragma unroll
        for (int t = 0; t < 4; ++t) {
            bf16x4 pb;
#pragma unroll
            for (int rr = 0; rr < 4; ++rr) pb[rr] = (short)f2bf(acc[t][rr]);
            f32x4 y = mfma16x16x16bf16(mf, pb, zero);
            // y[rr] = Yt[k = grp*4+rr][node][fo = t*16+col]
#pragma unroll
            for (int rr = 0; rr < 4; ++rr)
                Yt[(size_t)(grp*4 + rr)*NN*FF + (size_t)node*FF + t*16 + col] = f2bf(y[rr]);
        }
    }
}

// ---------------------------------------------------------------------------
// CSR build: count -> scan (3 phase) -> fill
// ---------------------------------------------------------------------------
__global__ __launch_bounds__(256) void count_kernel(const int* __restrict__ rows,
                                                    int* __restrict__ cnt)
{
    int i = blockIdx.x*256 + threadIdx.x;
    const int stride = gridDim.x*256;
    for (; i < NEDGE; i += stride) {
        const int j = i >> 17;            // EE = 2^17
        atomicAdd(&cnt[j*NN + rows[i]], 1);
    }
}

__global__ __launch_bounds__(256) void scan1(const int* __restrict__ cnt, int* __restrict__ part)
{
    __shared__ int sd[256];
    const int t = threadIdx.x;
    const int base = blockIdx.x*1024 + t*4;
    int s = 0;
    if (base + 3 < NR) {
        int4 v = *reinterpret_cast<const int4*>(cnt + base);
        s = v.x + v.y + v.z + v.w;
    } else if (base < NR) {
        for (int u = 0; u < 4; ++u) if (base + u < NR) s += cnt[base + u];
    }
    sd[t] = s; __syncthreads();
#pragma unroll
    for (int o = 128; o > 0; o >>= 1) {
        if (t < o) sd[t] += sd[t + o];
        __syncthreads();
    }
    if (t == 0) part[blockIdx.x] = sd[0];
}

__global__ __launch_bounds__(1024) void scan2(int* __restrict__ part)
{
    __shared__ int sd[1024];
    const int t = threadIdx.x;
    sd[t] = (t < SCAN_NBLK) ? part[t] : 0;
    __syncthreads();
#pragma unroll
    for (int o = 1; o < 1024; o <<= 1) {
        int v = (t >= o) ? sd[t - o] : 0;
        __syncthreads();
        sd[t] += v;
        __syncthreads();
    }
    part[t] = (t == 0) ? 0 : sd[t - 1];   // exclusive block prefix
}

__global__ __launch_bounds__(256) void scan3(const int* __restrict__ cnt, const int* __restrict__ part,
                                             int* __restrict__ offs, int* __restrict__ cur)
{
    __shared__ int sd[256];
    const int t = threadIdx.x;
    const int base = blockIdx.x*1024 + t*4;
    int v0 = 0, v1 = 0, v2 = 0, v3 = 0;
    if (base + 3 < NR) {
        int4 v = *reinterpret_cast<const int4*>(cnt + base);
        v0 = v.x; v1 = v.y; v2 = v.z; v3 = v.w;
    } else if (base < NR) {
        v0 = cnt[base];
        if (base + 1 < NR) v1 = cnt[base + 1];
        if (base + 2 < NR) v2 = cnt[base + 2];
    }
    sd[t] = v0 + v1 + v2 + v3;
    __syncthreads();
#pragma unroll
    for (int o = 1; o < 256; o <<= 1) {
        int vv = (t >= o) ? sd[t - o] : 0;
        __syncthreads();
        sd[t] += vv;
        __syncthreads();
    }
    const int excl = (t == 0) ? 0 : sd[t - 1];
    const int off = part[blockIdx.x] + excl;
    const int o0 = off, o1 = off + v0, o2 = off + v0 + v1, o3 = off + v0 + v1 + v2;
    if (base + 3 < NR) {
        int4 ov; ov.x = o0; ov.y = o1; ov.z = o2; ov.w = o3;
        *reinterpret_cast<int4*>(offs + base) = ov;
        *reinterpret_cast<int4*>(cur + base) = ov;
    } else if (base < NR) {
        offs[base] = o0; cur[base] = o0;
        if (base + 1 < NR) { offs[base+1] = o1; cur[base+1] = o1; }
        if (base + 2 < NR) { offs[base+2] = o2; cur[base+2] = o2; }
    }
}

__global__ __launch_bounds__(256) void fill_kernel(const int* __restrict__ rows,
                                                   const int* __restrict__ cols,
                                                   const float* __restrict__ vals,
                                                   int* __restrict__ cur,
                                                   int2* __restrict__ csr)
{
    int i = blockIdx.x*256 + threadIdx.x;
    const int stride = gridDim.x*256;
    for (; i < NEDGE; i += stride) {
        const int j = i >> 17;
        const int pos = atomicAdd(&cur[j*NN + rows[i]], 1);
        int2 ent; ent.x = cols[i]; ent.y = __float_as_int(vals[i]);
        csr[pos] = ent;
    }
}

// ---------------------------------------------------------------------------
// K2: out[k][r][:] = sum_{d=0..2, j=k-d>=0} M[k,j] * sum_{e in CSR_j(r)} v_e * Yt[k][c_e][:]
// One wave handles 4 rows (16 lanes x 4 floats each). Pure gather, no atomics.
// ---------------------------------------------------------------------------
__global__ __launch_bounds__(256) void k2_spmm(
    const unsigned short* __restrict__ Yt, const float* __restrict__ M,
    const int* __restrict__ offs, const int* __restrict__ cnt,
    const int2* __restrict__ csr, float* __restrict__ out)
{
    const int wid  = threadIdx.x >> 6;
    const int lane = threadIdx.x & 63;
    const int grp  = lane >> 4;   // row within wave
    const int fq   = lane & 15;   // feature quad: f = fq*4 .. fq*4+3
    const int k = blockIdx.y;
    const int r = blockIdx.x*16 + wid*4 + grp;    // 3125*16 = 50000 exact
    const unsigned short* Yb = Yt + (size_t)k*NN*FF;

    int bases[3], ns[3]; float wgt[3];
#pragma unroll
    for (int d = 0; d < 3; ++d) {
        const int j = k - d;
        const bool ok = (j >= 0);
        const int jc = ok ? j : 0;
        bases[d] = offs[jc*NN + r];
        ns[d]    = ok ? cnt[jc*NN + r] : 0;
        wgt[d]   = ok ? M[k*16 + jc] : 0.f;
    }

    float a0 = 0.f, a1 = 0.f, a2 = 0.f, a3 = 0.f;
#pragma unroll
    for (int d = 0; d < 3; ++d) {
        const int n = ns[d];
        const int base = bases[d];
        const float w = wgt[d];
        int2 ent;
        if (n > 0) ent = csr[base];
        for (int e = 0; e < n; ++e) {
            int2 nxt = ent;
            if (e + 1 < n) nxt = csr[base + e + 1];   // 1-ahead prefetch of next edge
            const float wv = w * __int_as_float(ent.y);
            const uint2 uv = *reinterpret_cast<const uint2*>(Yb + (size_t)ent.x*FF + fq*4);
            a0 = fmaf(wv, __uint_as_float((uv.x & 0xFFFFu) << 16), a0);
            a1 = fmaf(wv, __uint_as_float(uv.x & 0xFFFF0000u), a1);
            a2 = fmaf(wv, __uint_as_float((uv.y & 0xFFFFu) << 16), a2);
            a3 = fmaf(wv, __uint_as_float(uv.y & 0xFFFF0000u), a3);
            ent = nxt;
        }
    }
    float4 res; res.x = a0; res.y = a1; res.z = a2; res.w = a3;
    *reinterpret_cast<float4*>(out + ((size_t)k*NN + r)*FF + fq*4) = res;
}

// ---------------------------------------------------------------------------
extern "C" void kernel_launch(void* const* d_in, const int* in_sizes, int n_in,
                              void* d_out, int out_size, void* d_ws, size_t ws_size,
                              hipStream_t stream) {
    (void)in_sizes; (void)n_in; (void)out_size; (void)ws_size;
    const float* x     = (const float*)d_in[0];
    const float* M     = (const float*)d_in[1];
    const float* avals = (const float*)d_in[2];
    const float* W     = (const float*)d_in[3];
    const int*   arows = (const int*)d_in[4];
    const int*   acols = (const int*)d_in[5];
    float* out = (float*)d_out;

    // workspace carve (total ~128.8 MB)
    char* ws = (char*)d_ws;
    size_t o = 0;
    unsigned short* Yt = (unsigned short*)(ws + o); o += (size_t)TT*NN*FF*2;  // 102.4 MB
    o = (o + 255) & ~(size_t)255;
    int* cnt  = (int*)(ws + o); o += (size_t)NR*4; o = (o + 255) & ~(size_t)255;
    int* offs = (int*)(ws + o); o += (size_t)NR*4; o = (o + 255) & ~(size_t)255;
    int* cur  = (int*)(ws + o); o += (size_t)NR*4; o = (o + 255) & ~(size_t)255;
    int* part = (int*)(ws + o); o += 4096;          o = (o + 255) & ~(size_t)255;
    int2* csr = (int2*)(ws + o);                    // 16.8 MB

    hipMemsetAsync(cnt, 0, (size_t)NR*4, stream);
    hipLaunchKernelGGL(k1_proj_mix, dim3(2048), dim3(256), 0, stream, x, M, W, Yt);
    hipLaunchKernelGGL(count_kernel, dim3(2048), dim3(256), 0, stream, arows, cnt);
    hipLaunchKernelGGL(scan1, dim3(SCAN_NBLK), dim3(256), 0, stream, cnt, part);
    hipLaunchKernelGGL(scan2, dim3(1), dim3(1024), 0, stream, part);
    hipLaunchKernelGGL(scan3, dim3(SCAN_NBLK), dim3(256), 0, stream, cnt, part, offs, cur);
    hipLaunchKernelGGL(fill_kernel, dim3(2048), dim3(256), 0, stream, arows, acols, avals, cur, csr);
    hipLaunchKernelGGL(k2_spmm, dim3(3125, 16), dim3(256), 0, stream, Yt, M, offs, cnt, csr, out);
}